// Round 7
// baseline (1052.287 us; speedup 1.0000x reference)
//
#include <hip/hip_runtime.h>

// CTAttention: octree dilated window attention, MI355X gfx950.
// fused(f32->bf16 + QKV GEMM, prefetch-pipelined) -> windowed MFMA attention -> proj GEMM.
// Dilation reshuffle is the row permutation p(w,k) = (w/4)*96 + k*4 + (w%4).

#define N_TOK 500000
#define NA    500064          // ceil(N/96)*96
#define MP    500096          // NA rounded up to 128-row GEMM tiles
#define MT    3907            // MP / 128 mtiles
#define MT8   3912            // mtiles padded to multiple of 8 (XCD swizzle)
#define CDIM  256
#define KWIN  24
#define NWIN  20836           // NA / 24
#define HEADS 8
#define SCALE_F 0.17677669529663689f

typedef __attribute__((ext_vector_type(8))) short bf16x8;
typedef __attribute__((ext_vector_type(4))) float f32x4;

__device__ __forceinline__ unsigned short f2b(float f) {
    unsigned int u = __float_as_uint(f);
    u += 0x7fffu + ((u >> 16) & 1u);        // round-to-nearest-even
    return (unsigned short)(u >> 16);
}

#define GLOAD_LDS16(gsrc, ldst) \
    __builtin_amdgcn_global_load_lds((const __attribute__((address_space(1))) void*)(gsrc), \
                                     (__attribute__((address_space(3))) void*)(ldst), 16, 0, 0)

// ---------------- weight conversion ----------------

__global__ __launch_bounds__(256) void cvt_w_kernel(const float* __restrict__ src,
                                                    unsigned short* __restrict__ dst, int n8) {
    int i = blockIdx.x * 256 + threadIdx.x;
    if (i >= n8) return;
    float4 a = ((const float4*)src)[i * 2];
    float4 b = ((const float4*)src)[i * 2 + 1];
    uint4 o;
    o.x = (unsigned)f2b(a.x) | ((unsigned)f2b(a.y) << 16);
    o.y = (unsigned)f2b(a.z) | ((unsigned)f2b(a.w) << 16);
    o.z = (unsigned)f2b(b.x) | ((unsigned)f2b(b.y) << 16);
    o.w = (unsigned)f2b(b.z) | ((unsigned)f2b(b.w) << 16);
    ((uint4*)dst)[i] = o;
}

__global__ __launch_bounds__(256) void zero_pad_kernel(unsigned short* __restrict__ dst) {
    // zero attnB rows [N_TOK, MP)
    int i = blockIdx.x * 256 + threadIdx.x;
    if (i < (MP - N_TOK) * CDIM / 8)
        *(uint4*)(dst + (size_t)N_TOK * CDIM + (size_t)i * 8) = make_uint4(0u, 0u, 0u, 0u);
}

// ---------------- fused QKV GEMM: qkv[M][768] = bf16(A32[M][256]) * Wt[768][256]^T + b ----
// 128x128 tile, BK=64, 4 waves (2x2 of 64x64), mfma_f32_16x16x32_bf16.
// Prefetch pipeline: next-step A loads (regs) + B global_load_lds DMA (double-buffered)
// are issued BEFORE the current step's MFMA phase; A convert+ds_write after barrier.

__global__ __launch_bounds__(256, 3) void qkv_gemm_kernel(const float* __restrict__ A32,
                                                          const unsigned short* __restrict__ Bt,
                                                          const float* __restrict__ bias,
                                                          unsigned short* __restrict__ out) {
    __shared__ unsigned short ldsA[128 * 64];
    __shared__ unsigned short ldsB[2][128 * 64];
    const int l = blockIdx.x;
    const int s = l >> 3;
    const int mtile = (l & 7) + 8 * (s / 6);
    const int ntile = s - (s / 6) * 6;
    if (mtile >= MT) return;

    const int tid  = threadIdx.x;
    const int lane = tid & 63;
    const int wv   = tid >> 6;
    const int wr   = wv >> 1, wc = wv & 1;

    f32x4 acc[4][4];
    #pragma unroll
    for (int i = 0; i < 4; ++i)
        #pragma unroll
        for (int j = 0; j < 4; ++j)
            #pragma unroll
            for (int r = 0; r < 4; ++r) acc[i][j][r] = 0.f;

    const char*  bbase = (const char*)(Bt + (size_t)ntile * 128 * CDIM);
    const int lrow8 = lane >> 3;
    const int lcolb = (lane & 7) * 16;
    const int arow  = tid >> 4;            // 0..15 row-within-16-group
    const int acol  = (tid & 15) * 4;      // f32 col
    const int growb = mtile * 128;
    const bool full_tile = (growb + 128 <= N_TOK);
    const float* aptr = A32 + (size_t)growb * CDIM + acol;

#define LOAD_A(kt_, dst_)                                                            \
    do {                                                                             \
        if (full_tile) {                                                             \
            _Pragma("unroll")                                                        \
            for (int i_ = 0; i_ < 8; ++i_)                                           \
                dst_[i_] = *(const float4*)(aptr + (size_t)(i_ * 16 + arow) * CDIM + (kt_) * 64); \
        } else {                                                                     \
            _Pragma("unroll")                                                        \
            for (int i_ = 0; i_ < 8; ++i_) {                                         \
                int rg_ = growb + i_ * 16 + arow;                                    \
                int rc_ = rg_ < N_TOK ? rg_ : (N_TOK - 1);                           \
                dst_[i_] = *(const float4*)(A32 + (size_t)rc_ * CDIM + (kt_) * 64 + acol); \
            }                                                                        \
            _Pragma("unroll")                                                        \
            for (int i_ = 0; i_ < 8; ++i_)                                           \
                if (growb + i_ * 16 + arow >= N_TOK) dst_[i_] = make_float4(0.f, 0.f, 0.f, 0.f); \
        }                                                                            \
    } while (0)

#define WRITE_A(src_)                                                                \
    do {                                                                             \
        _Pragma("unroll")                                                            \
        for (int i_ = 0; i_ < 8; ++i_) {                                             \
            float4 a_ = src_[i_];                                                    \
            uint2 o_;                                                                \
            o_.x = (unsigned)f2b(a_.x) | ((unsigned)f2b(a_.y) << 16);                \
            o_.y = (unsigned)f2b(a_.z) | ((unsigned)f2b(a_.w) << 16);                \
            *(uint2*)&ldsA[(i_ * 16 + arow) * 64 + acol] = o_;                       \
        }                                                                            \
    } while (0)

#define ISSUE_B(kt_, buf_)                                                           \
    do {                                                                             \
        _Pragma("unroll")                                                            \
        for (int c_ = 0; c_ < 4; ++c_) {                                             \
            int chunk_ = wv * 4 + c_;                                                \
            int row_ = chunk_ * 8 + lrow8;                                           \
            GLOAD_LDS16(bbase + (size_t)row_ * 512 + (kt_) * 128 + lcolb, &ldsB[buf_][chunk_ * 512]); \
        }                                                                            \
    } while (0)

    // prologue: stage kt=0
    {
        float4 a0[8];
        LOAD_A(0, a0);
        ISSUE_B(0, 0);
        WRITE_A(a0);
    }
    __syncthreads();

    #pragma unroll
    for (int kt = 0; kt < 4; ++kt) {
        float4 anext[8];
        if (kt < 3) {
            LOAD_A(kt + 1, anext);          // issued first: convert waits vmcnt(4), B stays in flight
            ISSUE_B(kt + 1, (kt + 1) & 1);
        }
        #pragma unroll
        for (int ks = 0; ks < 2; ++ks) {
            const int kb = ks * 32 + (lane >> 4) * 8;
            bf16x8 af[4], bfr[4];
            #pragma unroll
            for (int i = 0; i < 4; ++i) {
                af[i]  = *(const bf16x8*)&ldsA[(wr * 64 + i * 16 + (lane & 15)) * 64 + kb];
                bfr[i] = *(const bf16x8*)&ldsB[kt & 1][(wc * 64 + i * 16 + (lane & 15)) * 64 + kb];
            }
            #pragma unroll
            for (int i = 0; i < 4; ++i)
                #pragma unroll
                for (int j = 0; j < 4; ++j)
                    acc[i][j] = __builtin_amdgcn_mfma_f32_16x16x32_bf16(af[i], bfr[j], acc[i][j], 0, 0, 0);
        }
        __syncthreads();                    // all waves done reading ldsA
        if (kt < 3) {
            WRITE_A(anext);
            __syncthreads();                // ldsA writes visible; B DMA drained
        }
    }
#undef LOAD_A
#undef WRITE_A
#undef ISSUE_B

    // epilogue: C/D layout col=lane&15, row=(lane>>4)*4+reg
    #pragma unroll
    for (int i = 0; i < 4; ++i) {
        int row0 = mtile * 128 + wr * 64 + i * 16 + ((lane >> 4) << 2);
        #pragma unroll
        for (int j = 0; j < 4; ++j) {
            int col = ntile * 128 + wc * 64 + j * 16 + (lane & 15);
            float bv = bias[col];
            #pragma unroll
            for (int r = 0; r < 4; ++r)
                out[(size_t)(row0 + r) * 768 + col] = f2b(acc[i][j][r] + bv);
        }
    }
}

// ---------------- proj GEMM: out[M][256] = A[M][256] * Bt[256][256]^T + bias (f32 out) ----

__global__ __launch_bounds__(256, 3) void proj_gemm_kernel(const unsigned short* __restrict__ A,
                                                           const unsigned short* __restrict__ Bt,
                                                           const float* __restrict__ bias,
                                                           float* __restrict__ out) {
    __shared__ unsigned short ldsA[128 * 64];
    __shared__ unsigned short ldsB[128 * 64];
    const int l = blockIdx.x;
    const int s = l >> 3;
    const int mtile = (l & 7) + 8 * (s >> 1);
    const int ntile = s & 1;
    if (mtile >= MT) return;

    const int tid  = threadIdx.x;
    const int lane = tid & 63;
    const int wv   = tid >> 6;
    const int wr   = wv >> 1, wc = wv & 1;

    f32x4 acc[4][4];
    #pragma unroll
    for (int i = 0; i < 4; ++i)
        #pragma unroll
        for (int j = 0; j < 4; ++j)
            #pragma unroll
            for (int r = 0; r < 4; ++r) acc[i][j][r] = 0.f;

    const char* abase = (const char*)(A  + (size_t)mtile * 128 * CDIM);
    const char* bbase = (const char*)(Bt + (size_t)ntile * 128 * CDIM);
    const int lrow8 = lane >> 3;
    const int lcolb = (lane & 7) * 16;

    for (int kt = 0; kt < 4; ++kt) {
        const int kb_byte = kt * 128;
        #pragma unroll
        for (int c = 0; c < 4; ++c) {
            int chunk = wv * 4 + c;
            int row = chunk * 8 + lrow8;
            GLOAD_LDS16(abase + (size_t)row * 512 + kb_byte + lcolb, &ldsA[chunk * 512]);
        }
        #pragma unroll
        for (int c = 0; c < 4; ++c) {
            int chunk = wv * 4 + c;
            int row = chunk * 8 + lrow8;
            GLOAD_LDS16(bbase + (size_t)row * 512 + kb_byte + lcolb, &ldsB[chunk * 512]);
        }
        __syncthreads();
        #pragma unroll
        for (int ks = 0; ks < 2; ++ks) {
            const int kb = ks * 32 + (lane >> 4) * 8;
            bf16x8 af[4], bfr[4];
            #pragma unroll
            for (int i = 0; i < 4; ++i) {
                af[i]  = *(const bf16x8*)&ldsA[(wr * 64 + i * 16 + (lane & 15)) * 64 + kb];
                bfr[i] = *(const bf16x8*)&ldsB[(wc * 64 + i * 16 + (lane & 15)) * 64 + kb];
            }
            #pragma unroll
            for (int i = 0; i < 4; ++i)
                #pragma unroll
                for (int j = 0; j < 4; ++j)
                    acc[i][j] = __builtin_amdgcn_mfma_f32_16x16x32_bf16(af[i], bfr[j], acc[i][j], 0, 0, 0);
        }
        __syncthreads();
    }

    #pragma unroll
    for (int i = 0; i < 4; ++i) {
        int row0 = mtile * 128 + wr * 64 + i * 16 + ((lane >> 4) << 2);
        #pragma unroll
        for (int j = 0; j < 4; ++j) {
            int col = ntile * 128 + wc * 64 + j * 16 + (lane & 15);
            float bv = bias[col];
            #pragma unroll
            for (int r = 0; r < 4; ++r) {
                int row = row0 + r;
                if (row < N_TOK) out[(size_t)row * CDIM + col] = acc[i][j][r] + bv;
            }
        }
    }
}

// ---------------- windowed MFMA attention, one wave = one (window, head) ----------------
// No staging, no barriers. Q/K: coalesced bf16x8 global loads. V: 16 scalar u16
// global loads (k-transposed gather). P transposes through wave-private swizzled LDS.

__global__ __launch_bounds__(256) void attn_kernel(const unsigned short* __restrict__ qkv,
                                                   const int* __restrict__ batch_idx,
                                                   unsigned short* __restrict__ attn_out) {
    __shared__ unsigned short sP[4][32 * 64];       // per-wave 32x32 P, row stride 64 elems (128B)
    const int tid  = threadIdx.x;
    const int lane = tid & 63;
    const int ws_  = tid >> 6;
    const int wid  = blockIdx.x * 4 + ws_;          // (window, head) task
    const int w = wid >> 3, h = wid & 7;
    const int gw = w >> 2, dd = w & 3;
    const int lrow = lane & 15, lg = lane >> 4;
    const int pbase = gw * 96 + dd;                 // token row = pbase + r*4, r in [0,32)

    // ---- Q, K fragments: A/B layout row|n = lane&15, k = lg*8 + 0..7 ----
    bf16x8 Qf[2], Kf[2];
    #pragma unroll
    for (int t = 0; t < 2; ++t) {
        size_t p = (size_t)(pbase + (t * 16 + lrow) * 4);
        const unsigned short* bp = qkv + p * 768 + h * 32 + lg * 8;
        Qf[t] = *(const bf16x8*)bp;
        Kf[t] = *(const bf16x8*)(bp + 256);
    }

    // ---- V gather (issue early; latency hides under QK^T + softmax) ----
    unsigned short v0[8], v1[8];
    #pragma unroll
    for (int j2 = 0; j2 < 8; ++j2) {
        size_t p = (size_t)(pbase + (lg * 8 + j2) * 4);
        const unsigned short* vp = qkv + p * 768 + 512 + h * 32 + lrow;
        v0[j2] = vp[0];
        v1[j2] = vp[16];
    }

    // ---- batch ids (sentinels: pad-q = -1, pad-k = -2, never equal) ----
    int bq[2];
    #pragma unroll
    for (int j = 0; j < 2; ++j) {
        int r = j * 16 + lrow;
        int p = pbase + r * 4;
        bq[j] = (r < KWIN && p < N_TOK) ? batch_idx[p] : -1;
    }
    int bk[2][4];
    #pragma unroll
    for (int i = 0; i < 2; ++i)
        #pragma unroll
        for (int rr = 0; rr < 4; ++rr) {
            int r = i * 16 + lg * 4 + rr;
            int p = pbase + r * 4;
            bk[i][rr] = (r < KWIN && p < N_TOK) ? batch_idx[p] : -2;
        }

    // ---- QK^T swapped: S^T[k][q]; D col = q = lane&15, row = k = lg*4+r ----
    f32x4 accS[2][2];
    #pragma unroll
    for (int i = 0; i < 2; ++i)
        #pragma unroll
        for (int j = 0; j < 2; ++j)
            #pragma unroll
            for (int r = 0; r < 4; ++r) accS[i][j][r] = 0.f;
    #pragma unroll
    for (int i = 0; i < 2; ++i)
        #pragma unroll
        for (int j = 0; j < 2; ++j)
            accS[i][j] = __builtin_amdgcn_mfma_f32_16x16x32_bf16(Kf[i], Qf[j], accS[i][j], 0, 0, 0);

    // ---- masked softmax over k, per q column (q = j*16+lrow) ----
    float sv[2][2][4];
    float mx[2] = { -3.0e38f, -3.0e38f };
    #pragma unroll
    for (int i = 0; i < 2; ++i)
        #pragma unroll
        for (int j = 0; j < 2; ++j)
            #pragma unroll
            for (int rr = 0; rr < 4; ++rr) {
                float val = (bk[i][rr] == bq[j]) ? accS[i][j][rr] * SCALE_F : -1.0e9f;
                sv[i][j][rr] = val;
                mx[j] = fmaxf(mx[j], val);
            }
    mx[0] = fmaxf(mx[0], __shfl_xor(mx[0], 16)); mx[0] = fmaxf(mx[0], __shfl_xor(mx[0], 32));
    mx[1] = fmaxf(mx[1], __shfl_xor(mx[1], 16)); mx[1] = fmaxf(mx[1], __shfl_xor(mx[1], 32));
    float sm[2] = { 0.f, 0.f };
    #pragma unroll
    for (int i = 0; i < 2; ++i)
        #pragma unroll
        for (int j = 0; j < 2; ++j)
            #pragma unroll
            for (int rr = 0; rr < 4; ++rr) {
                float e = __expf(sv[i][j][rr] - mx[j]);
                sv[i][j][rr] = e;
                sm[j] += e;
            }
    sm[0] += __shfl_xor(sm[0], 16); sm[0] += __shfl_xor(sm[0], 32);
    sm[1] += __shfl_xor(sm[1], 16); sm[1] += __shfl_xor(sm[1], 32);
    float inv[2] = { 1.f / sm[0], 1.f / sm[1] };

    // ---- P -> LDS (bf16, row-XOR swizzled), then read A-fragments ----
    char* pb = (char*)sP[ws_];
    const int swz = (lrow & 7) << 4;                // q&7 == lrow&7 for q = j*16+lrow
    #pragma unroll
    for (int j = 0; j < 2; ++j) {
        int q = j * 16 + lrow;
        #pragma unroll
        for (int i = 0; i < 2; ++i) {
            unsigned lo = (unsigned)f2b(sv[i][j][0] * inv[j]) | ((unsigned)f2b(sv[i][j][1] * inv[j]) << 16);
            unsigned hi = (unsigned)f2b(sv[i][j][2] * inv[j]) | ((unsigned)f2b(sv[i][j][3] * inv[j]) << 16);
            *(uint2*)(pb + q * 128 + ((i * 32 + lg * 8) ^ swz)) = make_uint2(lo, hi);
        }
    }
    bf16x8 AP[2];
    #pragma unroll
    for (int jj = 0; jj < 2; ++jj)
        AP[jj] = *(const bf16x8*)(pb + (jj * 16 + lrow) * 128 + ((lg * 16) ^ swz));

    // ---- PV: B fragments from V gather; D row = q = lg*4+r, col = d = lane&15 ----
    union { bf16x8 v; unsigned short s[8]; } B0, B1;
    #pragma unroll
    for (int j2 = 0; j2 < 8; ++j2) { B0.s[j2] = v0[j2]; B1.s[j2] = v1[j2]; }
    f32x4 accO[2][2];
    #pragma unroll
    for (int i = 0; i < 2; ++i)
        #pragma unroll
        for (int j = 0; j < 2; ++j)
            #pragma unroll
            for (int r = 0; r < 4; ++r) accO[i][j][r] = 0.f;
    #pragma unroll
    for (int jj = 0; jj < 2; ++jj) {
        accO[jj][0] = __builtin_amdgcn_mfma_f32_16x16x32_bf16(AP[jj], B0.v, accO[jj][0], 0, 0, 0);
        accO[jj][1] = __builtin_amdgcn_mfma_f32_16x16x32_bf16(AP[jj], B1.v, accO[jj][1], 0, 0, 0);
    }

    // ---- store: q = jj*16 + lg*4 + rr, channel = h*32 + {lrow, 16+lrow} ----
    #pragma unroll
    for (int jj = 0; jj < 2; ++jj)
        #pragma unroll
        for (int rr = 0; rr < 4; ++rr) {
            int q = jj * 16 + lg * 4 + rr;
            int p = pbase + q * 4;
            if (q < KWIN && p < N_TOK) {
                unsigned short* op = attn_out + (size_t)p * CDIM + h * 32;
                op[lrow]      = f2b(accO[jj][0][rr]);
                op[16 + lrow] = f2b(accO[jj][1][rr]);
            }
        }
}

// ---------------- host launch ----------------

extern "C" void kernel_launch(void* const* d_in, const int* in_sizes, int n_in,
                              void* d_out, int out_size, void* d_ws, size_t ws_size,
                              hipStream_t stream) {
    const float* data    = (const float*)d_in[0];
    const float* qkv_w   = (const float*)d_in[1];
    const float* qkv_b   = (const float*)d_in[2];
    const float* proj_w  = (const float*)d_in[3];
    const float* proj_b  = (const float*)d_in[4];
    const int*   batch_i = (const int*)d_in[5];

    char* ws = (char*)d_ws;
    size_t off = 0;
    unsigned short* qkvB   = (unsigned short*)(ws + off); off += (size_t)MP * 768 * 2;   // 768 MB
    unsigned short* attnB  = (unsigned short*)(ws + off); off += (size_t)MP * CDIM * 2;  // 256 MB
    unsigned short* wqkvB  = (unsigned short*)(ws + off); off += (size_t)768 * 256 * 2;
    unsigned short* wprojB = (unsigned short*)(ws + off); off += (size_t)256 * 256 * 2;
    if (ws_size < off) return;

    cvt_w_kernel<<<(768 * 256 / 8 + 255) / 256, 256, 0, stream>>>(qkv_w, wqkvB, 768 * 256 / 8);
    cvt_w_kernel<<<(256 * 256 / 8 + 255) / 256, 256, 0, stream>>>(proj_w, wprojB, 256 * 256 / 8);
    zero_pad_kernel<<<12, 256, 0, stream>>>(attnB);

    qkv_gemm_kernel<<<MT8 * 6, 256, 0, stream>>>(data, wqkvB, qkv_b, qkvB);
    attn_kernel<<<NWIN * HEADS / 4, 256, 0, stream>>>(qkvB, batch_i, attnB);
    proj_gemm_kernel<<<MT8 * 2, 256, 0, stream>>>(attnB, wprojB, proj_b, (float*)d_out);
}

// Round 8
// 905.012 us; speedup vs baseline: 1.1627x; 1.1627x over previous
//
#include <hip/hip_runtime.h>

// CTAttention: octree dilated window attention, MI355X gfx950.
// fused(f32->bf16 + QKV GEMM) -> windowed MFMA attention -> proj GEMM.
// Dilation reshuffle is the row permutation p(w,k) = (w/4)*96 + k*4 + (w%4).
// GEMM LDS tiles use T2 XOR-swizzle (byte-col ^= (row&7)<<4): linear gload_lds
// dest + pre-swizzled global source + swizzled ds_read (rule #21).

#define N_TOK 500000
#define NA    500064          // ceil(N/96)*96
#define MP    500096          // NA rounded up to 128-row GEMM tiles
#define MT    3907            // MP / 128 mtiles
#define MT8   3912            // mtiles padded to multiple of 8 (XCD swizzle)
#define CDIM  256
#define KWIN  24
#define NWIN  20836           // NA / 24
#define HEADS 8
#define SCALE_F 0.17677669529663689f

typedef __attribute__((ext_vector_type(8))) short bf16x8;
typedef __attribute__((ext_vector_type(4))) float f32x4;

__device__ __forceinline__ unsigned short f2b(float f) {
    unsigned int u = __float_as_uint(f);
    u += 0x7fffu + ((u >> 16) & 1u);        // round-to-nearest-even
    return (unsigned short)(u >> 16);
}

#define GLOAD_LDS16(gsrc, ldst) \
    __builtin_amdgcn_global_load_lds((const __attribute__((address_space(1))) void*)(gsrc), \
                                     (__attribute__((address_space(3))) void*)(ldst), 16, 0, 0)

// ---------------- weight conversion ----------------

__global__ __launch_bounds__(256) void cvt_w_kernel(const float* __restrict__ src,
                                                    unsigned short* __restrict__ dst, int n8) {
    int i = blockIdx.x * 256 + threadIdx.x;
    if (i >= n8) return;
    float4 a = ((const float4*)src)[i * 2];
    float4 b = ((const float4*)src)[i * 2 + 1];
    uint4 o;
    o.x = (unsigned)f2b(a.x) | ((unsigned)f2b(a.y) << 16);
    o.y = (unsigned)f2b(a.z) | ((unsigned)f2b(a.w) << 16);
    o.z = (unsigned)f2b(b.x) | ((unsigned)f2b(b.y) << 16);
    o.w = (unsigned)f2b(b.z) | ((unsigned)f2b(b.w) << 16);
    ((uint4*)dst)[i] = o;
}

__global__ __launch_bounds__(256) void zero_pad_kernel(unsigned short* __restrict__ dst) {
    // zero attnB rows [N_TOK, MP)
    int i = blockIdx.x * 256 + threadIdx.x;
    if (i < (MP - N_TOK) * CDIM / 8)
        *(uint4*)(dst + (size_t)N_TOK * CDIM + (size_t)i * 8) = make_uint4(0u, 0u, 0u, 0u);
}

// ---------------- fused QKV GEMM: qkv[M][768] = bf16(A32[M][256]) * Wt[768][256]^T + b ----
// 128x128 tile, BK=64, 4 waves (2x2 of 64x64), mfma_f32_16x16x32_bf16.
// A: batched unconditional f32 loads -> cvt -> swizzled ds_write.
// B: global_load_lds with pre-swizzled source. XCD-bijective block swizzle.

__global__ __launch_bounds__(256, 3) void qkv_gemm_kernel(const float* __restrict__ A32,
                                                          const unsigned short* __restrict__ Bt,
                                                          const float* __restrict__ bias,
                                                          unsigned short* __restrict__ out) {
    __shared__ unsigned short ldsA[128 * 64];
    __shared__ unsigned short ldsB[128 * 64];
    const int l = blockIdx.x;
    const int s = l >> 3;
    const int mtile = (l & 7) + 8 * (s / 6);
    const int ntile = s - (s / 6) * 6;
    if (mtile >= MT) return;

    const int tid  = threadIdx.x;
    const int lane = tid & 63;
    const int wv   = tid >> 6;
    const int wr   = wv >> 1, wc = wv & 1;

    f32x4 acc[4][4];
    #pragma unroll
    for (int i = 0; i < 4; ++i)
        #pragma unroll
        for (int j = 0; j < 4; ++j)
            #pragma unroll
            for (int r = 0; r < 4; ++r) acc[i][j][r] = 0.f;

    const char*  bbase = (const char*)(Bt + (size_t)ntile * 128 * CDIM);
    const int lrow8 = lane >> 3;
    const int lcolb_sw = (((lane & 7) ^ lrow8) << 4);   // pre-swizzled source col-bytes
    const int arow  = tid >> 4;            // 0..15 row-within-16-group
    const int acol  = (tid & 15) * 4;      // f32 col
    const int awz   = ((tid >> 4) & 7) << 4;            // (row&7)<<4 for A ds_write
    const int growb = mtile * 128;
    const bool full_tile = (growb + 128 <= N_TOK);
    char* ldsA_b = (char*)ldsA;
    const int lrow = lane & 15, lg = lane >> 4;
    const int swzr = (lrow & 7) << 4;                   // read-side XOR (row&7 == lrow&7)

    for (int kt = 0; kt < 4; ++kt) {
        // B: async DMA, source pre-swizzled so linear-dest image is swizzled
        #pragma unroll
        for (int c = 0; c < 4; ++c) {
            int chunk = wv * 4 + c;
            int row = chunk * 8 + lrow8;
            GLOAD_LDS16(bbase + (size_t)row * 512 + kt * 128 + lcolb_sw, &ldsB[chunk * 512]);
        }
        // A phase 1: batched unconditional loads (all 8 in flight at once)
        float4 areg[8];
        if (full_tile) {
            #pragma unroll
            for (int i = 0; i < 8; ++i) {
                int row_g = growb + i * 16 + arow;
                areg[i] = *(const float4*)(A32 + (size_t)row_g * CDIM + kt * 64 + acol);
            }
        } else {
            #pragma unroll
            for (int i = 0; i < 8; ++i) {
                int row_g = growb + i * 16 + arow;
                int row_c = row_g < N_TOK ? row_g : (N_TOK - 1);   // VALU select, load stays unconditional
                areg[i] = *(const float4*)(A32 + (size_t)row_c * CDIM + kt * 64 + acol);
            }
            #pragma unroll
            for (int i = 0; i < 8; ++i)
                if (growb + i * 16 + arow >= N_TOK) areg[i] = make_float4(0.f, 0.f, 0.f, 0.f);
        }
        // A phase 2: convert + swizzled LDS write
        #pragma unroll
        for (int i = 0; i < 8; ++i) {
            float4 a = areg[i];
            uint2 o;
            o.x = (unsigned)f2b(a.x) | ((unsigned)f2b(a.y) << 16);
            o.y = (unsigned)f2b(a.z) | ((unsigned)f2b(a.w) << 16);
            *(uint2*)(ldsA_b + (i * 16 + arow) * 128 + (((tid & 15) * 8) ^ awz)) = o;
        }
        __syncthreads();                    // drains vmcnt (DMA) + lgkm (ds_write)
        #pragma unroll
        for (int ks = 0; ks < 2; ++ks) {
            const int kbyte = ks * 64 + lg * 16;
            bf16x8 af[4], bfr[4];
            #pragma unroll
            for (int i = 0; i < 4; ++i) {
                int ra = wr * 64 + i * 16 + lrow;
                int rb = wc * 64 + i * 16 + lrow;
                af[i]  = *(const bf16x8*)(ldsA_b + ra * 128 + (kbyte ^ swzr));
                bfr[i] = *(const bf16x8*)((const char*)ldsB + rb * 128 + (kbyte ^ swzr));
            }
            #pragma unroll
            for (int i = 0; i < 4; ++i)
                #pragma unroll
                for (int j = 0; j < 4; ++j)
                    acc[i][j] = __builtin_amdgcn_mfma_f32_16x16x32_bf16(af[i], bfr[j], acc[i][j], 0, 0, 0);
        }
        __syncthreads();
    }

    // epilogue: C/D layout col=lane&15, row=(lane>>4)*4+reg
    #pragma unroll
    for (int i = 0; i < 4; ++i) {
        int row0 = mtile * 128 + wr * 64 + i * 16 + ((lane >> 4) << 2);
        #pragma unroll
        for (int j = 0; j < 4; ++j) {
            int col = ntile * 128 + wc * 64 + j * 16 + (lane & 15);
            float bv = bias[col];
            #pragma unroll
            for (int r = 0; r < 4; ++r)
                out[(size_t)(row0 + r) * 768 + col] = f2b(acc[i][j][r] + bv);
        }
    }
}

// ---------------- proj GEMM: out[M][256] = A[M][256] * Bt[256][256]^T + bias (f32 out) ----

__global__ __launch_bounds__(256, 3) void proj_gemm_kernel(const unsigned short* __restrict__ A,
                                                           const unsigned short* __restrict__ Bt,
                                                           const float* __restrict__ bias,
                                                           float* __restrict__ out) {
    __shared__ unsigned short ldsA[128 * 64];
    __shared__ unsigned short ldsB[128 * 64];
    const int l = blockIdx.x;
    const int s = l >> 3;
    const int mtile = (l & 7) + 8 * (s >> 1);
    const int ntile = s & 1;
    if (mtile >= MT) return;

    const int tid  = threadIdx.x;
    const int lane = tid & 63;
    const int wv   = tid >> 6;
    const int wr   = wv >> 1, wc = wv & 1;

    f32x4 acc[4][4];
    #pragma unroll
    for (int i = 0; i < 4; ++i)
        #pragma unroll
        for (int j = 0; j < 4; ++j)
            #pragma unroll
            for (int r = 0; r < 4; ++r) acc[i][j][r] = 0.f;

    const char* abase = (const char*)(A  + (size_t)mtile * 128 * CDIM);
    const char* bbase = (const char*)(Bt + (size_t)ntile * 128 * CDIM);
    const int lrow8 = lane >> 3;
    const int lcolb_sw = (((lane & 7) ^ lrow8) << 4);   // pre-swizzled source col-bytes
    const int lrow = lane & 15, lg = lane >> 4;
    const int swzr = (lrow & 7) << 4;

    for (int kt = 0; kt < 4; ++kt) {
        const int kb_byte = kt * 128;
        #pragma unroll
        for (int c = 0; c < 4; ++c) {
            int chunk = wv * 4 + c;
            int row = chunk * 8 + lrow8;
            GLOAD_LDS16(abase + (size_t)row * 512 + kb_byte + lcolb_sw, &ldsA[chunk * 512]);
        }
        #pragma unroll
        for (int c = 0; c < 4; ++c) {
            int chunk = wv * 4 + c;
            int row = chunk * 8 + lrow8;
            GLOAD_LDS16(bbase + (size_t)row * 512 + kb_byte + lcolb_sw, &ldsB[chunk * 512]);
        }
        __syncthreads();
        #pragma unroll
        for (int ks = 0; ks < 2; ++ks) {
            const int kbyte = ks * 64 + lg * 16;
            bf16x8 af[4], bfr[4];
            #pragma unroll
            for (int i = 0; i < 4; ++i) {
                int ra = wr * 64 + i * 16 + lrow;
                int rb = wc * 64 + i * 16 + lrow;
                af[i]  = *(const bf16x8*)((const char*)ldsA + ra * 128 + (kbyte ^ swzr));
                bfr[i] = *(const bf16x8*)((const char*)ldsB + rb * 128 + (kbyte ^ swzr));
            }
            #pragma unroll
            for (int i = 0; i < 4; ++i)
                #pragma unroll
                for (int j = 0; j < 4; ++j)
                    acc[i][j] = __builtin_amdgcn_mfma_f32_16x16x32_bf16(af[i], bfr[j], acc[i][j], 0, 0, 0);
        }
        __syncthreads();
    }

    #pragma unroll
    for (int i = 0; i < 4; ++i) {
        int row0 = mtile * 128 + wr * 64 + i * 16 + ((lane >> 4) << 2);
        #pragma unroll
        for (int j = 0; j < 4; ++j) {
            int col = ntile * 128 + wc * 64 + j * 16 + (lane & 15);
            float bv = bias[col];
            #pragma unroll
            for (int r = 0; r < 4; ++r) {
                int row = row0 + r;
                if (row < N_TOK) out[(size_t)row * CDIM + col] = acc[i][j][r] + bv;
            }
        }
    }
}

// ---------------- windowed MFMA attention, one wave = one (window, head) ----------------
// No staging, no barriers. Q/K: coalesced bf16x8 global loads. V: 16 scalar u16
// global loads (k-transposed gather). P transposes through wave-private swizzled LDS.

__global__ __launch_bounds__(256) void attn_kernel(const unsigned short* __restrict__ qkv,
                                                   const int* __restrict__ batch_idx,
                                                   unsigned short* __restrict__ attn_out) {
    __shared__ unsigned short sP[4][32 * 64];       // per-wave 32x32 P, row stride 64 elems (128B)
    const int tid  = threadIdx.x;
    const int lane = tid & 63;
    const int ws_  = tid >> 6;
    const int wid  = blockIdx.x * 4 + ws_;          // (window, head) task
    const int w = wid >> 3, h = wid & 7;
    const int gw = w >> 2, dd = w & 3;
    const int lrow = lane & 15, lg = lane >> 4;
    const int pbase = gw * 96 + dd;                 // token row = pbase + r*4, r in [0,32)

    // ---- Q, K fragments: A/B layout row|n = lane&15, k = lg*8 + 0..7 ----
    bf16x8 Qf[2], Kf[2];
    #pragma unroll
    for (int t = 0; t < 2; ++t) {
        size_t p = (size_t)(pbase + (t * 16 + lrow) * 4);
        const unsigned short* bp = qkv + p * 768 + h * 32 + lg * 8;
        Qf[t] = *(const bf16x8*)bp;
        Kf[t] = *(const bf16x8*)(bp + 256);
    }

    // ---- V gather (issue early; latency hides under QK^T + softmax) ----
    unsigned short v0[8], v1[8];
    #pragma unroll
    for (int j2 = 0; j2 < 8; ++j2) {
        size_t p = (size_t)(pbase + (lg * 8 + j2) * 4);
        const unsigned short* vp = qkv + p * 768 + 512 + h * 32 + lrow;
        v0[j2] = vp[0];
        v1[j2] = vp[16];
    }

    // ---- batch ids (sentinels: pad-q = -1, pad-k = -2, never equal) ----
    int bq[2];
    #pragma unroll
    for (int j = 0; j < 2; ++j) {
        int r = j * 16 + lrow;
        int p = pbase + r * 4;
        bq[j] = (r < KWIN && p < N_TOK) ? batch_idx[p] : -1;
    }
    int bk[2][4];
    #pragma unroll
    for (int i = 0; i < 2; ++i)
        #pragma unroll
        for (int rr = 0; rr < 4; ++rr) {
            int r = i * 16 + lg * 4 + rr;
            int p = pbase + r * 4;
            bk[i][rr] = (r < KWIN && p < N_TOK) ? batch_idx[p] : -2;
        }

    // ---- QK^T swapped: S^T[k][q]; D col = q = lane&15, row = k = lg*4+r ----
    f32x4 accS[2][2];
    #pragma unroll
    for (int i = 0; i < 2; ++i)
        #pragma unroll
        for (int j = 0; j < 2; ++j)
            #pragma unroll
            for (int r = 0; r < 4; ++r) accS[i][j][r] = 0.f;
    #pragma unroll
    for (int i = 0; i < 2; ++i)
        #pragma unroll
        for (int j = 0; j < 2; ++j)
            accS[i][j] = __builtin_amdgcn_mfma_f32_16x16x32_bf16(Kf[i], Qf[j], accS[i][j], 0, 0, 0);

    // ---- masked softmax over k, per q column (q = j*16+lrow) ----
    float sv[2][2][4];
    float mx[2] = { -3.0e38f, -3.0e38f };
    #pragma unroll
    for (int i = 0; i < 2; ++i)
        #pragma unroll
        for (int j = 0; j < 2; ++j)
            #pragma unroll
            for (int rr = 0; rr < 4; ++rr) {
                float val = (bk[i][rr] == bq[j]) ? accS[i][j][rr] * SCALE_F : -1.0e9f;
                sv[i][j][rr] = val;
                mx[j] = fmaxf(mx[j], val);
            }
    mx[0] = fmaxf(mx[0], __shfl_xor(mx[0], 16)); mx[0] = fmaxf(mx[0], __shfl_xor(mx[0], 32));
    mx[1] = fmaxf(mx[1], __shfl_xor(mx[1], 16)); mx[1] = fmaxf(mx[1], __shfl_xor(mx[1], 32));
    float sm[2] = { 0.f, 0.f };
    #pragma unroll
    for (int i = 0; i < 2; ++i)
        #pragma unroll
        for (int j = 0; j < 2; ++j)
            #pragma unroll
            for (int rr = 0; rr < 4; ++rr) {
                float e = __expf(sv[i][j][rr] - mx[j]);
                sv[i][j][rr] = e;
                sm[j] += e;
            }
    sm[0] += __shfl_xor(sm[0], 16); sm[0] += __shfl_xor(sm[0], 32);
    sm[1] += __shfl_xor(sm[1], 16); sm[1] += __shfl_xor(sm[1], 32);
    float inv[2] = { 1.f / sm[0], 1.f / sm[1] };

    // ---- P -> LDS (bf16, row-XOR swizzled), then read A-fragments ----
    char* pb = (char*)sP[ws_];
    const int swz = (lrow & 7) << 4;                // q&7 == lrow&7 for q = j*16+lrow
    #pragma unroll
    for (int j = 0; j < 2; ++j) {
        int q = j * 16 + lrow;
        #pragma unroll
        for (int i = 0; i < 2; ++i) {
            unsigned lo = (unsigned)f2b(sv[i][j][0] * inv[j]) | ((unsigned)f2b(sv[i][j][1] * inv[j]) << 16);
            unsigned hi = (unsigned)f2b(sv[i][j][2] * inv[j]) | ((unsigned)f2b(sv[i][j][3] * inv[j]) << 16);
            *(uint2*)(pb + q * 128 + ((i * 32 + lg * 8) ^ swz)) = make_uint2(lo, hi);
        }
    }
    bf16x8 AP[2];
    #pragma unroll
    for (int jj = 0; jj < 2; ++jj)
        AP[jj] = *(const bf16x8*)(pb + (jj * 16 + lrow) * 128 + ((lg * 16) ^ swz));

    // ---- PV: B fragments from V gather; D row = q = lg*4+r, col = d = lane&15 ----
    union { bf16x8 v; unsigned short s[8]; } B0, B1;
    #pragma unroll
    for (int j2 = 0; j2 < 8; ++j2) { B0.s[j2] = v0[j2]; B1.s[j2] = v1[j2]; }
    f32x4 accO[2][2];
    #pragma unroll
    for (int i = 0; i < 2; ++i)
        #pragma unroll
        for (int j = 0; j < 2; ++j)
            #pragma unroll
            for (int r = 0; r < 4; ++r) accO[i][j][r] = 0.f;
    #pragma unroll
    for (int jj = 0; jj < 2; ++jj) {
        accO[jj][0] = __builtin_amdgcn_mfma_f32_16x16x32_bf16(AP[jj], B0.v, accO[jj][0], 0, 0, 0);
        accO[jj][1] = __builtin_amdgcn_mfma_f32_16x16x32_bf16(AP[jj], B1.v, accO[jj][1], 0, 0, 0);
    }

    // ---- store: q = jj*16 + lg*4 + rr, channel = h*32 + {lrow, 16+lrow} ----
    #pragma unroll
    for (int jj = 0; jj < 2; ++jj)
        #pragma unroll
        for (int rr = 0; rr < 4; ++rr) {
            int q = jj * 16 + lg * 4 + rr;
            int p = pbase + q * 4;
            if (q < KWIN && p < N_TOK) {
                unsigned short* op = attn_out + (size_t)p * CDIM + h * 32;
                op[lrow]      = f2b(accO[jj][0][rr]);
                op[16 + lrow] = f2b(accO[jj][1][rr]);
            }
        }
}

// ---------------- host launch ----------------

extern "C" void kernel_launch(void* const* d_in, const int* in_sizes, int n_in,
                              void* d_out, int out_size, void* d_ws, size_t ws_size,
                              hipStream_t stream) {
    const float* data    = (const float*)d_in[0];
    const float* qkv_w   = (const float*)d_in[1];
    const float* qkv_b   = (const float*)d_in[2];
    const float* proj_w  = (const float*)d_in[3];
    const float* proj_b  = (const float*)d_in[4];
    const int*   batch_i = (const int*)d_in[5];

    char* ws = (char*)d_ws;
    size_t off = 0;
    unsigned short* qkvB   = (unsigned short*)(ws + off); off += (size_t)MP * 768 * 2;   // 768 MB
    unsigned short* attnB  = (unsigned short*)(ws + off); off += (size_t)MP * CDIM * 2;  // 256 MB
    unsigned short* wqkvB  = (unsigned short*)(ws + off); off += (size_t)768 * 256 * 2;
    unsigned short* wprojB = (unsigned short*)(ws + off); off += (size_t)256 * 256 * 2;
    if (ws_size < off) return;

    cvt_w_kernel<<<(768 * 256 / 8 + 255) / 256, 256, 0, stream>>>(qkv_w, wqkvB, 768 * 256 / 8);
    cvt_w_kernel<<<(256 * 256 / 8 + 255) / 256, 256, 0, stream>>>(proj_w, wprojB, 256 * 256 / 8);
    zero_pad_kernel<<<12, 256, 0, stream>>>(attnB);

    qkv_gemm_kernel<<<MT8 * 6, 256, 0, stream>>>(data, wqkvB, qkv_b, qkvB);
    attn_kernel<<<NWIN * HEADS / 4, 256, 0, stream>>>(qkvB, batch_i, attnB);
    proj_gemm_kernel<<<MT8 * 2, 256, 0, stream>>>(attnB, wprojB, proj_b, (float*)d_out);
}